// Round 6
// baseline (335.589 us; speedup 1.0000x reference)
//
#include <hip/hip_runtime.h>
#include <limits.h>

// CCL 8-connectivity on 4096x4096 binary image (prob > 0.5).
// Output: int32 labels, label = (min linear index in component) + 1, bg = 0.
//
// Local phase: BKE 2x2-block union-find in LDS on PIXEL KEYS (node key =
// block's min fg pixel local index). Union-by-min over keys => root key IS
// the tile-component's min pixel (no separate minpix aggregation).
// Then: fused cross-tile border unions (UNCONDITIONAL — R4's dedup had a
// circular-reliance bug at tile corners), then fused resolve+convert.

constexpr int HH = 4096;
constexpr int WW = 4096;
constexpr int NPIX = HH * WW;
constexpr int TILE = 64;
constexpr int BDIM = TILE / 2;        // 32 blocks per tile dim
constexpr int NBLK = BDIM * BDIM;     // 1024

// ---------------------------------------------------- global union-find ---
__device__ __forceinline__ int find_root_g(int* P, int x) {
    while (true) {
        int p = P[x];
        if (p == x) return x;
        int gp = P[p];
        if (gp == p) return p;
        atomicMin(&P[x], gp);   // path halving (monotone => race-safe)
        x = gp;
    }
}

__device__ __forceinline__ void unite_g(int* P, int a, int b) {
    while (true) {
        a = find_root_g(P, a);
        b = find_root_g(P, b);
        if (a == b) return;
        if (a > b) { int t = a; a = b; b = t; }
        int old = atomicMin(&P[b], a);
        if (old == b) return;
        b = old;
    }
}

// ------------------------------------------- LDS union-find on pixel keys -
// key = local pixel index lr*64+lc (0..4095). Block of a key:
__device__ __forceinline__ int lkey2b(int k) {
    return ((k >> 7) << 5) | ((k & 63) >> 1);   // (lr>>1)*32 + (lc>>1)
}

// invariant: stored values are always canonical keys (k == bkey(lkey2b(k))),
// since initial values are canonical and links store root keys. atomicMin
// over pixel-raster order => monotone, lock-free safe.
__device__ __forceinline__ int find_l(int* par, int bk) {
    while (true) {
        int xb = lkey2b(bk);
        int p = par[xb];
        if (p == bk) return bk;          // root
        int pb = lkey2b(p);
        int gp = par[pb];
        if (gp == p) return p;           // parent is root
        atomicMin(&par[xb], gp);         // path halving
        bk = gp;
    }
}

__device__ __forceinline__ void unite_l(int* par, int ka, int kb) {
    while (true) {
        ka = find_l(par, ka);
        kb = find_l(par, kb);
        if (ka == kb) return;
        if (ka > kb) { int t = ka; ka = kb; kb = t; }
        int old = atomicMin(&par[lkey2b(kb)], ka);
        if (old == kb) return;
        kb = old;
    }
}

// block's own key from its mask: min fg pixel (bit0=+0,bit1=+1,bit2=+64,bit3=+65)
__device__ __forceinline__ int bkey(int b, int m) {
    int base = ((b >> 5) << 7) + ((b & 31) << 1);   // (2i)*64 + 2j
    int off = (m & 1) ? 0 : (m & 2) ? 1 : (m & 4) ? 64 : 65;
    return base + off;
}

// ------------------------------------------- local (per-tile) BKE CCL -----
// Block masks: bit0=(r,c) bit1=(r,c+1) bit2=(r+1,c) bit3=(r+1,c+1).
// Left col=0x5, right col=0xA, top row=0x3, bottom row=0xC.
__global__ __launch_bounds__(256) void ccl_local_bke(const float* __restrict__ prob,
                                                     int* __restrict__ P) {
    __shared__ int bmask[NBLK];
    __shared__ int par[NBLK];
    const int tile_c = blockIdx.x * TILE;
    const int tile_r = blockIdx.y * TILE;
    const int tid = threadIdx.x;

    int nib[4];
    #pragma unroll
    for (int k = 0; k < 4; ++k) {
        int b = tid + 256 * k;
        int i = b >> 5, j = b & 31;
        const float* rp = prob + (size_t)(tile_r + 2 * i) * WW + tile_c + 2 * j;
        float2 t = *reinterpret_cast<const float2*>(rp);
        float2 bo = *reinterpret_cast<const float2*>(rp + WW);
        int m = (t.x > 0.5f ? 1 : 0) | (t.y > 0.5f ? 2 : 0) |
                (bo.x > 0.5f ? 4 : 0) | (bo.y > 0.5f ? 8 : 0);
        nib[k] = m;
        bmask[b] = m;
        par[b] = m ? bkey(b, m) : -1;
    }
    __syncthreads();

    #pragma unroll
    for (int k = 0; k < 4; ++k) {
        int m = nib[k];
        if (!m) continue;
        int b = tid + 256 * k;
        int i = b >> 5, j = b & 31;
        int mk = bkey(b, m);
        if (j > 0) {
            int wm = bmask[b - 1];
            if ((m & 0x5) && (wm & 0xA)) unite_l(par, mk, bkey(b - 1, wm));
        }
        if (i > 0) {
            int nm = bmask[b - BDIM];
            if ((m & 0x3) && (nm & 0xC)) unite_l(par, mk, bkey(b - BDIM, nm));
            if (j > 0) {
                int nwm = bmask[b - BDIM - 1];
                if ((m & 0x1) && (nwm & 0x8)) unite_l(par, mk, bkey(b - BDIM - 1, nwm));
            }
            if (j < BDIM - 1) {
                int nem = bmask[b - BDIM + 1];
                if ((m & 0x2) && (nem & 0x4)) unite_l(par, mk, bkey(b - BDIM + 1, nem));
            }
        }
    }
    __syncthreads();

    #pragma unroll
    for (int k = 0; k < 4; ++k) {
        int b = tid + 256 * k;
        int i = b >> 5, j = b & 31;
        int gr = tile_r + 2 * i, gc = tile_c + 2 * j;
        int m = nib[k];
        int2 top = make_int2(-1, -1), bot = make_int2(-1, -1);
        if (m) {
            int x = bkey(b, m);
            while (true) {               // read-only chase (par is stable now)
                int p = par[lkey2b(x)];
                if (p == x) break;
                x = p;
            }
            int g = (tile_r + (x >> 6)) * WW + tile_c + (x & 63);
            top.x = (m & 1) ? g : -1;
            top.y = (m & 2) ? g : -1;
            bot.x = (m & 4) ? g : -1;
            bot.y = (m & 8) ? g : -1;
        }
        *reinterpret_cast<int2*>(P + (size_t)gr * WW + gc) = top;
        *reinterpret_cast<int2*>(P + (size_t)(gr + 1) * WW + gc) = bot;
    }
}

// ------------------------- fused cross-tile border fix (unconditional) ----
// y=0: horizontal tile boundaries (rows r=64,128,...): N, or NW/NE when N bg.
// y=1: vertical tile boundaries (cols c=64,128,...): W, NW, SW.
// These link sets are exactly R2/R3's proven-correct ones; no dedup.
__global__ void ccl_border(int* __restrict__ P) {
    int idx = blockIdx.x * 256 + threadIdx.x;
    if (blockIdx.y == 0) {
        int c = idx & (WW - 1);
        int r = ((idx >> 12) + 1) * TILE;
        int i = r * WW + c;
        if (P[i] < 0) return;
        int j = i - WW;
        if (P[j] >= 0) {
            unite_g(P, i, j);     // NW/NE transitively covered via row-above W-links
        } else {
            if (c > 0      && P[j - 1] >= 0) unite_g(P, i, j - 1);
            if (c < WW - 1 && P[j + 1] >= 0) unite_g(P, i, j + 1);
        }
    } else {
        int r = idx & (HH - 1);
        int c = ((idx >> 12) + 1) * TILE;
        int i = r * WW + c;
        if (P[i] < 0) return;
        if (P[i - 1] >= 0) unite_g(P, i, i - 1);                          // W
        if (r > 0      && P[i - WW - 1] >= 0) unite_g(P, i, i - WW - 1);  // NW
        if (r < HH - 1 && P[i + WW - 1] >= 0) unite_g(P, i, i + WW - 1);  // SW
    }
}

// ------------------------------------------ resolve + convert (to d_out) --
__device__ __forceinline__ int resolve_memo(const int* __restrict__ P, int x,
                                            int& ci, int& co) {
    if (x < 0) return 0;
    if (x == ci) return co;
    int r = x;
    while (true) { int p = P[r]; if (p == r) break; r = p; }
    ci = x; co = r + 1;
    return co;
}

__global__ void ccl_final4(const int* __restrict__ P, int* __restrict__ out) {
    int i = (blockIdx.x * blockDim.x + threadIdx.x) * 4;
    int4 v = *reinterpret_cast<const int4*>(P + i);
    int ci = -2, co = 0;
    int4 o;
    o.x = resolve_memo(P, v.x, ci, co);
    o.y = resolve_memo(P, v.y, ci, co);
    o.z = resolve_memo(P, v.z, ci, co);
    o.w = resolve_memo(P, v.w, ci, co);
    *reinterpret_cast<int4*>(out + i) = o;
}

// ---------------------------- fallback path (P aliases d_out, no ws) ------
__global__ void ccl_compress(int* __restrict__ P) {
    int i = blockIdx.x * blockDim.x + threadIdx.x;
    int x = P[i];
    if (x < 0) return;
    while (true) { int p = P[x]; if (p == x) break; x = p; }
    P[i] = x;
}

__global__ void ccl_convert(int* __restrict__ P) {
    int i = (blockIdx.x * blockDim.x + threadIdx.x) * 4;
    int4 v = *reinterpret_cast<const int4*>(P + i);
    v.x = (v.x < 0) ? 0 : v.x + 1;
    v.y = (v.y < 0) ? 0 : v.y + 1;
    v.z = (v.z < 0) ? 0 : v.z + 1;
    v.w = (v.w < 0) ? 0 : v.w + 1;
    *reinterpret_cast<int4*>(P + i) = v;
}

// ---------------------------------------------------------------- launch --
extern "C" void kernel_launch(void* const* d_in, const int* in_sizes, int n_in,
                              void* d_out, int out_size, void* d_ws, size_t ws_size,
                              hipStream_t stream) {
    const float* prob = (const float*)d_in[0];
    const bool have_ws = ws_size >= (size_t)NPIX * sizeof(int);
    int* P = have_ws ? (int*)d_ws : (int*)d_out;

    ccl_local_bke<<<dim3(WW / TILE, HH / TILE), dim3(256), 0, stream>>>(prob, P);

    // fused borders: y=0 horizontal rows (63*4096 px), y=1 vertical cols
    ccl_border<<<dim3((HH / TILE - 1) * WW / 256, 2), dim3(256), 0, stream>>>(P);

    if (have_ws) {
        ccl_final4<<<dim3(NPIX / 4 / 256), dim3(256), 0, stream>>>(P, (int*)d_out);
    } else {
        ccl_compress<<<dim3(NPIX / 256), dim3(256), 0, stream>>>(P);
        ccl_convert<<<dim3(NPIX / 4 / 256), dim3(256), 0, stream>>>(P);
    }
}

// Round 7
// 278.210 us; speedup vs baseline: 1.2062x; 1.2062x over previous
//
#include <hip/hip_runtime.h>
#include <limits.h>

// CCL 8-connectivity on 4096x4096 binary image (prob > 0.5).
// Output: int32 labels, label = (min linear index in component) + 1, bg = 0.
//
// Local phase: BKE 2x2-block union-find in LDS on PIXEL KEYS over 128x128
// tiles (node key = block's min fg pixel local index; union-by-min => root
// key IS the tile-component's min pixel).
// Border phase: BLOCK-LEVEL unites across the 31+31 tile boundaries — each
// thread handles one 2-pixel border segment, <=3 unites, completeness proven
// from performed unites + intra-tile 2-pixel local links only (no induction).
// Final: fused resolve+convert to d_out.

constexpr int HH = 4096;
constexpr int WW = 4096;
constexpr int NPIX = HH * WW;
constexpr int TILE = 128;
constexpr int BDIM = TILE / 2;        // 64 blocks per tile dim
constexpr int NBLK = BDIM * BDIM;     // 4096

// ---------------------------------------------------- global union-find ---
__device__ __forceinline__ int find_root_g(int* P, int x) {
    while (true) {
        int p = P[x];
        if (p == x) return x;
        int gp = P[p];
        if (gp == p) return p;
        atomicMin(&P[x], gp);   // path halving (monotone => race-safe)
        x = gp;
    }
}

__device__ __forceinline__ void unite_g(int* P, int a, int b) {
    while (true) {
        a = find_root_g(P, a);
        b = find_root_g(P, b);
        if (a == b) return;
        if (a > b) { int t = a; a = b; b = t; }
        int old = atomicMin(&P[b], a);
        if (old == b) return;
        b = old;
    }
}

// ------------------------------------------- LDS union-find on pixel keys -
// key = local pixel index lr*128+lc (0..16383). Block of a key:
__device__ __forceinline__ int lkey2b(int k) {
    return ((k >> 8) << 6) | ((k & 127) >> 1);   // (lr>>1)*64 + (lc>>1)
}

// stored values are always canonical keys (block-min fg pixel); atomicMin
// over pixel-raster order => monotone, lock-free safe.
__device__ __forceinline__ int find_l(int* par, int bk) {
    while (true) {
        int xb = lkey2b(bk);
        int p = par[xb];
        if (p == bk) return bk;          // root
        int pb = lkey2b(p);
        int gp = par[pb];
        if (gp == p) return p;           // parent is root
        atomicMin(&par[xb], gp);         // path halving
        bk = gp;
    }
}

__device__ __forceinline__ void unite_l(int* par, int ka, int kb) {
    while (true) {
        ka = find_l(par, ka);
        kb = find_l(par, kb);
        if (ka == kb) return;
        if (ka > kb) { int t = ka; ka = kb; kb = t; }
        int old = atomicMin(&par[lkey2b(kb)], ka);
        if (old == kb) return;
        kb = old;
    }
}

// block's own key: min fg pixel (bit0=+0, bit1=+1, bit2=+128, bit3=+129)
__device__ __forceinline__ int bkey(int b, int m) {
    int base = ((b >> 6) << 8) + ((b & 63) << 1);   // (2i)*128 + 2j
    int off = (m & 1) ? 0 : (m & 2) ? 1 : (m & 4) ? 128 : 129;
    return base + off;
}

// ------------------------------------------- local (per-tile) BKE CCL -----
// Block masks: bit0=(r,c) bit1=(r,c+1) bit2=(r+1,c) bit3=(r+1,c+1).
// Left col=0x5, right col=0xA, top row=0x3, bottom row=0xC.
__global__ __launch_bounds__(256) void ccl_local_bke(const float* __restrict__ prob,
                                                     int* __restrict__ P) {
    __shared__ int bmask[NBLK];
    __shared__ int par[NBLK];
    const int tile_c = blockIdx.x * TILE;
    const int tile_r = blockIdx.y * TILE;
    const int tid = threadIdx.x;

    int nib[16];
    #pragma unroll
    for (int k = 0; k < 16; ++k) {
        int b = tid + 256 * k;
        int i = b >> 6, j = b & 63;
        const float* rp = prob + (size_t)(tile_r + 2 * i) * WW + tile_c + 2 * j;
        float2 t = *reinterpret_cast<const float2*>(rp);
        float2 bo = *reinterpret_cast<const float2*>(rp + WW);
        int m = (t.x > 0.5f ? 1 : 0) | (t.y > 0.5f ? 2 : 0) |
                (bo.x > 0.5f ? 4 : 0) | (bo.y > 0.5f ? 8 : 0);
        nib[k] = m;
        bmask[b] = m;
        par[b] = m ? bkey(b, m) : -1;
    }
    __syncthreads();

    #pragma unroll
    for (int k = 0; k < 16; ++k) {
        int m = nib[k];
        if (!m) continue;
        int b = tid + 256 * k;
        int i = b >> 6, j = b & 63;
        int mk = bkey(b, m);
        if (j > 0) {
            int wm = bmask[b - 1];
            if ((m & 0x5) && (wm & 0xA)) unite_l(par, mk, bkey(b - 1, wm));
        }
        if (i > 0) {
            int nm = bmask[b - BDIM];
            if ((m & 0x3) && (nm & 0xC)) unite_l(par, mk, bkey(b - BDIM, nm));
            if (j > 0) {
                int nwm = bmask[b - BDIM - 1];
                if ((m & 0x1) && (nwm & 0x8)) unite_l(par, mk, bkey(b - BDIM - 1, nwm));
            }
            if (j < BDIM - 1) {
                int nem = bmask[b - BDIM + 1];
                if ((m & 0x2) && (nem & 0x4)) unite_l(par, mk, bkey(b - BDIM + 1, nem));
            }
        }
    }
    __syncthreads();

    #pragma unroll
    for (int k = 0; k < 16; ++k) {
        int b = tid + 256 * k;
        int i = b >> 6, j = b & 63;
        int gr = tile_r + 2 * i, gc = tile_c + 2 * j;
        int m = nib[k];
        int2 top = make_int2(-1, -1), bot = make_int2(-1, -1);
        if (m) {
            int x = bkey(b, m);
            while (true) {               // read-only chase (par is stable now)
                int p = par[lkey2b(x)];
                if (p == x) break;
                x = p;
            }
            int g = (tile_r + (x >> 7)) * WW + tile_c + (x & 127);
            top.x = (m & 1) ? g : -1;
            top.y = (m & 2) ? g : -1;
            bot.x = (m & 4) ? g : -1;
            bot.y = (m & 8) ? g : -1;
        }
        *reinterpret_cast<int2*>(P + (size_t)gr * WW + gc) = top;
        *reinterpret_cast<int2*>(P + (size_t)(gr + 1) * WW + gc) = bot;
    }
}

// ----------------------- block-level cross-tile border unites -------------
// y=0: horizontal boundaries (rows r=128,...,3968). Thread = one 2-pixel
//   column pair {c0,c0+1}: column unite + two outer diagonals. Complete:
//   all |dc|<=1 cross pairs are either directly united or bridged by
//   intra-tile 2-pixel local links (c0 even => {c0,c0+1} same tile;
//   {(r-1,c0),(r-1,c0+1)} same tile).
// y=1: vertical boundaries (cols c=128,...): symmetric with rows.
__global__ void ccl_border(int* __restrict__ P) {
    int idx = blockIdx.x * 256 + threadIdx.x;
    int bidx = idx >> 11;          // which boundary (0..30)
    int t    = idx & 2047;         // 2-pixel segment within boundary
    if (blockIdx.y == 0) {
        int r = (bidx + 1) * TILE;
        int c0 = 2 * t;
        int2 d = *reinterpret_cast<const int2*>(P + (size_t)r * WW + c0);
        int2 u = *reinterpret_cast<const int2*>(P + (size_t)(r - 1) * WW + c0);
        bool d0 = d.x >= 0, d1 = d.y >= 0;
        bool u0 = u.x >= 0, u1 = u.y >= 0;
        if ((d0 | d1) && (u0 | u1)) {
            int pd = d0 ? r * WW + c0 : r * WW + c0 + 1;
            int pu = u0 ? (r - 1) * WW + c0 : (r - 1) * WW + c0 + 1;
            unite_g(P, pd, pu);
        }
        if (d0 && c0 > 0 && P[(size_t)(r - 1) * WW + c0 - 1] >= 0)
            unite_g(P, r * WW + c0, (r - 1) * WW + c0 - 1);
        if (d1 && c0 + 2 < WW && P[(size_t)(r - 1) * WW + c0 + 2] >= 0)
            unite_g(P, r * WW + c0 + 1, (r - 1) * WW + c0 + 2);
    } else {
        int c = (bidx + 1) * TILE;
        int r0 = 2 * t;
        bool e0 = P[(size_t)r0 * WW + c] >= 0;
        bool e1 = P[(size_t)(r0 + 1) * WW + c] >= 0;
        bool w0 = P[(size_t)r0 * WW + c - 1] >= 0;
        bool w1 = P[(size_t)(r0 + 1) * WW + c - 1] >= 0;
        if ((e0 | e1) && (w0 | w1)) {
            int pe = e0 ? r0 * WW + c : (r0 + 1) * WW + c;
            int pw = w0 ? r0 * WW + c - 1 : (r0 + 1) * WW + c - 1;
            unite_g(P, pe, pw);
        }
        if (e0 && r0 > 0 && P[(size_t)(r0 - 1) * WW + c - 1] >= 0)
            unite_g(P, r0 * WW + c, (r0 - 1) * WW + c - 1);
        if (e1 && r0 + 2 < HH && P[(size_t)(r0 + 2) * WW + c - 1] >= 0)
            unite_g(P, (r0 + 1) * WW + c, (r0 + 2) * WW + c - 1);
    }
}

// ------------------------------------------ resolve + convert (to d_out) --
__device__ __forceinline__ int resolve_memo(const int* __restrict__ P, int x,
                                            int& ci, int& co) {
    if (x < 0) return 0;
    if (x == ci) return co;
    int r = x;
    while (true) { int p = P[r]; if (p == r) break; r = p; }
    ci = x; co = r + 1;
    return co;
}

__global__ void ccl_final4(const int* __restrict__ P, int* __restrict__ out) {
    int i = (blockIdx.x * blockDim.x + threadIdx.x) * 4;
    int4 v = *reinterpret_cast<const int4*>(P + i);
    int ci = -2, co = 0;
    int4 o;
    o.x = resolve_memo(P, v.x, ci, co);
    o.y = resolve_memo(P, v.y, ci, co);
    o.z = resolve_memo(P, v.z, ci, co);
    o.w = resolve_memo(P, v.w, ci, co);
    *reinterpret_cast<int4*>(out + i) = o;
}

// ---------------------------- fallback path (P aliases d_out, no ws) ------
__global__ void ccl_compress(int* __restrict__ P) {
    int i = blockIdx.x * blockDim.x + threadIdx.x;
    int x = P[i];
    if (x < 0) return;
    while (true) { int p = P[x]; if (p == x) break; x = p; }
    P[i] = x;
}

__global__ void ccl_convert(int* __restrict__ P) {
    int i = (blockIdx.x * blockDim.x + threadIdx.x) * 4;
    int4 v = *reinterpret_cast<const int4*>(P + i);
    v.x = (v.x < 0) ? 0 : v.x + 1;
    v.y = (v.y < 0) ? 0 : v.y + 1;
    v.z = (v.z < 0) ? 0 : v.z + 1;
    v.w = (v.w < 0) ? 0 : v.w + 1;
    *reinterpret_cast<int4*>(P + i) = v;
}

// ---------------------------------------------------------------- launch --
extern "C" void kernel_launch(void* const* d_in, const int* in_sizes, int n_in,
                              void* d_out, int out_size, void* d_ws, size_t ws_size,
                              hipStream_t stream) {
    const float* prob = (const float*)d_in[0];
    const bool have_ws = ws_size >= (size_t)NPIX * sizeof(int);
    int* P = have_ws ? (int*)d_ws : (int*)d_out;

    ccl_local_bke<<<dim3(WW / TILE, HH / TILE), dim3(256), 0, stream>>>(prob, P);

    // block-level borders: (HH/TILE-1)=31 boundaries x 2048 segments, 2 families
    ccl_border<<<dim3((HH / TILE - 1) * (WW / 2) / 256, 2), dim3(256), 0, stream>>>(P);

    if (have_ws) {
        ccl_final4<<<dim3(NPIX / 4 / 256), dim3(256), 0, stream>>>(P, (int*)d_out);
    } else {
        ccl_compress<<<dim3(NPIX / 256), dim3(256), 0, stream>>>(P);
        ccl_convert<<<dim3(NPIX / 4 / 256), dim3(256), 0, stream>>>(P);
    }
}